// Round 7
// baseline (833.889 us; speedup 1.0000x reference)
//
#include <hip/hip_runtime.h>
#include <hip/hip_bf16.h>
#include <float.h>

#define NR    32768
#define DDIM  512
#define KC    8192
#define NTILE 64      // KC / 128 code-tiles

typedef __attribute__((ext_vector_type(8))) short short8;   // 8 bf16 = 4 VGPR
typedef __attribute__((ext_vector_type(4))) float f32x4;
typedef const __attribute__((address_space(1))) char gchar_t;
typedef __attribute__((address_space(3))) char lchar_t;

// pack two fp32 -> two bf16 (RNE) in one u32 (low word = first element)
__device__ inline unsigned cvt2(float a, float b) {
    __hip_bfloat162 h = __float22bfloat162_rn(float2{a, b});
    union { __hip_bfloat162 h; unsigned u; } v; v.h = h;
    return v.u;
}

// FUSED latents prep, LDS-staged: 32 rows per block.
//  phase1: coalesced fp32 reads -> bf16 granules staged in LDS (pad 33).
//  phase1b: rownorm per row -- chain BITWISE-IDENTICAL to all prior rounds
//           (scalar p[lane+i*64], same FMA order, same shfl reduce).
//  phase2: xb written in 512 B-contiguous runs (was 16 B/line partial-line
//          scatter -> ~4x HBM write amplification on 32 MB).
// xb layout (unchanged): granule (RB, og, r) at u32 RB*32768 + og*512 + r*4.
__global__ __launch_bounds__(256) void lat_prep_kernel(const float* __restrict__ src,
                                                       unsigned* __restrict__ xb,
                                                       float* __restrict__ sumx) {
    __shared__ uint4 st[64 * 33];            // [og][row], +1 pad granule
    const int t  = threadIdx.x;
    const int r0 = blockIdx.x * 32;          // first global row of this block

    // phase1: 2048 granules, coalesced 32 B/lane reads
#pragma unroll
    for (int i = 0; i < 8; ++i) {
        const int u  = i * 256 + t;          // granule index in block
        const int rr = u >> 6;               // row 0..31
        const int og = u & 63;               // octet 0..63
        const float* p = src + (size_t)(r0 + rr) * DDIM + og * 8;
        const float4 a = *(const float4*)p;
        const float4 b = *(const float4*)(p + 4);
        uint4 v;
        v.x = cvt2(a.x, a.y); v.y = cvt2(a.z, a.w);
        v.z = cvt2(b.x, b.y); v.w = cvt2(b.z, b.w);
        st[og * 33 + rr] = v;
    }

    // phase1b: rownorm, wave w handles rows 8w..8w+7 (reads are L2-hot)
    const int w = t >> 6, lane = t & 63;
#pragma unroll
    for (int s = 0; s < 8; ++s) {
        const int row = r0 + w * 8 + s;
        const float* p = src + (size_t)row * DDIM;
        float acc = 0.0f;
#pragma unroll
        for (int i = 0; i < DDIM / 64; ++i) {
            float v = p[lane + i * 64];
            acc = __builtin_fmaf(v, v, acc);
        }
#pragma unroll
        for (int off = 32; off > 0; off >>= 1) acc += __shfl_down(acc, off, 64);
        if (lane == 0) sumx[row] = acc;
    }
    __syncthreads();

    // phase2: 2048 granules out, 512 B-contiguous runs per og-column
    const int RB = r0 >> 7, rb = r0 & 127;
    uint4* xb4 = (uint4*)xb;
#pragma unroll
    for (int k = 0; k < 8; ++k) {
        const int u  = k * 256 + t;
        const int og = u >> 5, rr = u & 31;
        xb4[(size_t)RB * 8192 + og * 128 + rb + rr] = st[og * 33 + rr];
    }
}

// FUSED codebook prep, LDS-staged: 32 codebook rows per block. Same
// structure as lat_prep. ebT layout (unchanged): granule (g, k) at
// uint4 index g*8192 + k (fragment-major). Norm chain bitwise-identical.
__global__ __launch_bounds__(256) void emb_prep_kernel(const float* __restrict__ src,
                                                       unsigned* __restrict__ ebT,
                                                       float* __restrict__ sume) {
    __shared__ uint4 st[64 * 33];
    const int t  = threadIdx.x;
    const int k0 = blockIdx.x * 32;

#pragma unroll
    for (int i = 0; i < 8; ++i) {
        const int u  = i * 256 + t;
        const int rr = u >> 6;
        const int g  = u & 63;
        const float* p = src + (size_t)(k0 + rr) * DDIM + g * 8;
        const float4 a = *(const float4*)p;
        const float4 b = *(const float4*)(p + 4);
        uint4 v;
        v.x = cvt2(a.x, a.y); v.y = cvt2(a.z, a.w);
        v.z = cvt2(b.x, b.y); v.w = cvt2(b.z, b.w);
        st[g * 33 + rr] = v;
    }

    const int w = t >> 6, lane = t & 63;
#pragma unroll
    for (int s = 0; s < 8; ++s) {
        const int k = k0 + w * 8 + s;
        const float* p = src + (size_t)k * DDIM;
        float acc = 0.0f;
#pragma unroll
        for (int i = 0; i < DDIM / 64; ++i) {
            float v = p[lane + i * 64];
            acc = __builtin_fmaf(v, v, acc);
        }
#pragma unroll
        for (int off = 32; off > 0; off >>= 1) acc += __shfl_down(acc, off, 64);
        if (lane == 0) sume[k] = acc;
    }
    __syncthreads();

    uint4* eb4 = (uint4*)ebT;
#pragma unroll
    for (int kk = 0; kk < 8; ++kk) {
        const int u  = kk * 256 + t;
        const int g  = u >> 5, rr = u & 31;
        eb4[(size_t)g * 8192 + k0 + rr] = st[g * 33 + rr];
    }
}

__global__ __launch_bounds__(256) void semax_kernel(const float* __restrict__ sume,
                                                    float* __restrict__ semax) {
    __shared__ float red[256];
    float m = 0.f;
    for (int i = threadIdx.x; i < KC; i += 256) m = fmaxf(m, sume[i]);
    red[threadIdx.x] = m;
    __syncthreads();
    for (int s = 128; s > 0; s >>= 1) {
        if (threadIdx.x < s) red[threadIdx.x] = fmaxf(red[threadIdx.x], red[threadIdx.x + s]);
        __syncthreads();
    }
    if (threadIdx.x == 0) semax[0] = sqrtf(red[0]);
}

// bf16 MFMA approx-score GEMM + per-(row, code-tile) (min, argmin, 2ndmin).
// Round-7 change vs verified R2/R5 structure: wave tile 64x64 -> 128x32.
//  * B fragments become unique per wave (bptr depends on w) -> B VMEM traffic
//    halves (4 -> 2 GB); total L2 feed 6 -> 4 GB. Pipe model: VMEM was the
//    binding resource (~18 TB/s demanded), LDS second; this rebalances them.
//  * per-(row,col) MFMA accumulation chains bit-identical (same operands,
//    same it order -- only wave ownership moves). Epilogue min/2nd-min is a
//    multiset reduce (grouping-independent); merge adds one shfl level.
//  * VMEM group/iter = 2 X-DMA + 2 B = 4 -> s_waitcnt vmcnt(4) (never 0
//    in-loop), same counted-vmcnt depth-2 pattern as R2.
//  * A ds_reads 4 -> 8/iter (i spans 8): still 256 B-contiguous per 16-lane
//    group, conflict-free. If this round lands >=310 us, LDS is the binder.
//  * keep: octet-major xb (linear gload_lds), implicit nb%8 XCD pinning
//    (DO NOT remap blocks -- R3: FETCH x4), stats [nb][row].
__global__ __launch_bounds__(256) void gemm_filter_kernel(
        const unsigned* __restrict__ xb, const unsigned* __restrict__ ebT,
        const float* __restrict__ sume,
        float* __restrict__ lmin, float* __restrict__ l2nd, int* __restrict__ lidx) {
    __shared__ alignas(16) char smem[24576];   // X 3 x 8 KB; epilogue overlay

    const int tid  = threadIdx.x;
    const int nb   = blockIdx.x & (NTILE - 1);
    const int mb   = blockIdx.x >> 6;
    const int row0 = mb * 128, col0 = nb * 128;
    const int lane = tid & 63, w = tid >> 6;     // wave w: cols col0+32w..+31
    const int l15 = lane & 15, q4 = lane >> 4;   // q4 in [0,4)

    f32x4 acc[8][2];
#pragma unroll
    for (int i = 0; i < 8; ++i)
#pragma unroll
        for (int j = 0; j < 2; ++j) acc[i][j] = f32x4{0.f, 0.f, 0.f, 0.f};

    // X staging: region R = w*2+t, 1 KB linear per gload_lds (verbatim copy)
    const char* xg[2];
#pragma unroll
    for (int t = 0; t < 2; ++t)
        xg[t] = (const char*)xb + (size_t)mb * 131072 + ((w * 2 + t) << 10) + (lane << 4);
    // A-fragment byte offset: octet q4, row 16i+l15 (i in [0,8): all 128 rows)
    const int aoff = (q4 << 11) + (l15 << 4);    // + i*256

    // B global base: granule (g = q4, col = col0 + 32w + l15), u32 units
    const unsigned* bptr = ebT + ((size_t)(q4 * KC + col0 + 32 * w + l15)) * 4;
    // j-stride: 16 cols = 64 u32; tile-stride: 4*KC granules = 131072 u32

    short8 B[3][2];

    // prologue: stage tiles 0,1 (X -> LDS bufs 0,1; B -> reg sets 0,1)
#pragma unroll
    for (int p = 0; p < 2; ++p) {
#pragma unroll
        for (int t = 0; t < 2; ++t)
            __builtin_amdgcn_global_load_lds((gchar_t*)(xg[t] + p * 8192),
                (lchar_t*)(smem + p * 8192 + ((w * 2 + t) << 10) + (lane << 4)), 16, 0, 0);
        const unsigned* bn = bptr + (size_t)p * 131072;
#pragma unroll
        for (int j = 0; j < 2; ++j) B[p][j] = *(const short8*)(bn + j * 64);
    }

#pragma unroll
    for (int it = 0; it < 16; ++it) {
        // Drain tile it's issue-group (4 VMEM: 2 X-DMA + 2 B), keep tile
        // it+1's group (4) in flight across the barrier.
        if (it < 15) asm volatile("s_waitcnt vmcnt(4)" ::: "memory");
        else         asm volatile("s_waitcnt vmcnt(0)" ::: "memory");
        __builtin_amdgcn_sched_barrier(0);
        __builtin_amdgcn_s_barrier();
        __builtin_amdgcn_sched_barrier(0);
        // issue tile it+2: X into buf (it+2)%3 (released by barrier above)
        if (it + 2 < 16) {
#pragma unroll
            for (int t = 0; t < 2; ++t)
                __builtin_amdgcn_global_load_lds((gchar_t*)(xg[t] + (it + 2) * 8192),
                    (lchar_t*)(smem + ((it + 2) % 3) * 8192 + ((w * 2 + t) << 10) + (lane << 4)), 16, 0, 0);
            const unsigned* bn = bptr + (size_t)(it + 2) * 131072;
#pragma unroll
            for (int j = 0; j < 2; ++j) B[(it + 2) % 3][j] = *(const short8*)(bn + j * 64);
        }
        __builtin_amdgcn_sched_barrier(0);
        // compute tile it: 8 A-frags (128 rows) x 2 B-frags (32 cols)
        const char* Xc = smem + (it % 3) * 8192;
        short8 A[8];
#pragma unroll
        for (int i = 0; i < 8; ++i)
            A[i] = *(const short8*)(Xc + aoff + i * 256);
#pragma unroll
        for (int i = 0; i < 8; ++i)
#pragma unroll
            for (int j = 0; j < 2; ++j)
                acc[i][j] = __builtin_amdgcn_mfma_f32_16x16x32_bf16(A[i], B[it % 3][j], acc[i][j], 0, 0, 0);
    }

    // ---- epilogue: per-row (min, argmin, 2ndmin) over this 128-code tile.
    float se[2];
#pragma unroll
    for (int j = 0; j < 2; ++j) se[j] = sume[col0 + 32 * w + 16 * j + l15];

    __syncthreads();   // all waves done reading LDS before scratch overlays it
    float* pv1 = (float*)smem;             // [128][8]
    float* pv2 = (float*)(smem + 4096);    // [128][8]
    int*   pk1 = (int*)(smem + 8192);      // [128][8]

#pragma unroll
    for (int i = 0; i < 8; ++i) {
#pragma unroll
        for (int reg = 0; reg < 4; ++reg) {
            float v1 = FLT_MAX, v2 = FLT_MAX; int k1 = 0;
#pragma unroll
            for (int j = 0; j < 2; ++j) {
                const float s = __builtin_fmaf(-2.f, acc[i][j][reg], se[j]);
                const int c = col0 + 32 * w + 16 * j + l15;
                if (s < v1) { v2 = v1; v1 = s; k1 = c; }
                else        { v2 = fminf(v2, s); }
            }
            // merge 8 l15-lanes (3 levels): min/2nd over 16-code groups.
            // (exact ties leave l2nd==lmin -> rescore full-scans; moot)
#pragma unroll
            for (int m = 1; m <= 4; m <<= 1) {
                const float ov1 = __shfl_xor(v1, m, 64);
                const int   ok1 = __shfl_xor(k1, m, 64);
                const float ov2 = __shfl_xor(v2, m, 64);
                const float nv2 = fminf(fmaxf(v1, ov1), fminf(v2, ov2));
                if (ov1 < v1) { v1 = ov1; k1 = ok1; }
                v2 = nv2;
            }
            if ((l15 & 7) == 0) {
                const int rowl = 16 * i + 4 * q4 + reg;      // [0,128)
                const int c8   = 2 * w + (l15 >> 3);         // [0,8)
                const int slot = rowl * 8 + ((c8 + rowl) & 7);   // rotation swizzle
                pv1[slot] = v1; pv2[slot] = v2; pk1[slot] = k1;
            }
        }
    }
    __syncthreads();
    if (tid < 128) {
        float g1 = FLT_MAX, g2 = FLT_MAX; int gk = 0;
#pragma unroll
        for (int c = 0; c < 8; ++c) {
            const int slot = tid * 8 + ((c + tid) & 7);
            const float p1 = pv1[slot];
            const float p2 = pv2[slot];
            const int   pk = pk1[slot];
            if (p1 < g1) { g2 = fminf(g1, p2); g1 = p1; gk = pk; }
            else         { g2 = fminf(g2, p1); }
        }
        // transposed stat layout [nb][row]: 512 B contiguous per array
        const size_t o = (size_t)nb * NR + row0 + tid;
        lmin[o] = g1; l2nd[o] = g2; lidx[o] = gk;
    }
}

// exact rescore of provably-covering candidate set; one wave per row.
// margin = 2*(2^-7*||x||*||e||max + 6.5e-5): bf16-RNE dot error bound + two
// half-ulp(512) roundings in the exact formula, doubled for two-sidedness.
__global__ __launch_bounds__(256) void rescore_kernel(
        const float* __restrict__ x, const float* __restrict__ e,
        const float* __restrict__ sumx, const float* __restrict__ sume,
        const float* __restrict__ semax,
        const float* __restrict__ lmin, const float* __restrict__ l2nd,
        const int* __restrict__ lidx, int* __restrict__ inds) {
    __shared__ float xr[4][DDIM];
    __shared__ int list[4][64];

    const int w = threadIdx.x >> 6, lane = threadIdx.x & 63;
    const int row = blockIdx.x * 4 + w;

    // transposed stat layout [tile][row] (written coalesced by the gemm)
    const float lm = lmin[(size_t)lane * NR + row];
    const float l2 = l2nd[(size_t)lane * NR + row];
    const int   li = lidx[(size_t)lane * NR + row];

    float mr = lm;
#pragma unroll
    for (int m = 1; m < 64; m <<= 1) mr = fminf(mr, __shfl_xor(mr, m, 64));

    const float sx  = sumx[row];
    const float thr = mr + (0.0157f * sqrtf(sx) * semax[0] + 1.4e-4f);

    const bool single = (lm <= thr) && (l2 > thr);
    const unsigned long long bs = __ballot(single);
    const int pos = __popcll(bs & ((1ull << lane) - 1ull));
    if (single) list[w][pos] = li;
    const int nS = __popcll(bs);
    unsigned long long bf = __ballot(l2 <= thr);

    {
        const float* px = x + (size_t)row * DDIM + lane * 8;
        *(float4*)(&xr[w][lane * 8])     = *(const float4*)(px);
        *(float4*)(&xr[w][lane * 8 + 4]) = *(const float4*)(px + 4);
    }
    __syncthreads();

    float bd = FLT_MAX; int bk = 0x7fffffff;
    // exact dist: float4 loads, FMA order identical to all prior rounds
#define EVAL(KK)                                                             \
    {                                                                        \
        const int k_ = (KK);                                                 \
        const float4* ep4 = (const float4*)(e + ((size_t)k_ << 9));          \
        float dot = 0.f;                                                     \
        _Pragma("unroll 4")                                                  \
        for (int d4 = 0; d4 < 128; ++d4) {                                   \
            const float4 ev = ep4[d4];                                       \
            const float4 xv = *(const float4*)(&xr[w][d4 * 4]);              \
            dot = __builtin_fmaf(xv.x, ev.x, dot);                           \
            dot = __builtin_fmaf(xv.y, ev.y, dot);                           \
            dot = __builtin_fmaf(xv.z, ev.z, dot);                           \
            dot = __builtin_fmaf(xv.w, ev.w, dot);                           \
        }                                                                    \
        const float t1   = __fadd_rn(sx, sume[k_]);                          \
        const float dist = __fsub_rn(t1, __fadd_rn(dot, dot));               \
        if (dist < bd || (dist == bd && k_ < bk)) { bd = dist; bk = k_; }    \
    }

    if (lane < nS) EVAL(list[w][lane]);
    while (bf) {
        const int t = __ffsll((long long)bf) - 1;
        bf &= bf - 1;
        EVAL(128 * t + lane);
        EVAL(128 * t + 64 + lane);
    }
#undef EVAL

#pragma unroll
    for (int m = 1; m < 64; m <<= 1) {
        const float od = __shfl_xor(bd, m, 64);
        const int   ok = __shfl_xor(bk, m, 64);
        if (od < bd || (od == bd && ok < bk)) { bd = od; bk = ok; }
    }
    if (lane == 0) inds[row] = bk;
}

// out = x + (e[ind] - x), exact elementwise fp32 STE
__global__ __launch_bounds__(256) void writeout_kernel(const float* __restrict__ x,
                                                       const float* __restrict__ e,
                                                       const int* __restrict__ inds,
                                                       float* __restrict__ out) {
    const int t  = blockIdx.x * blockDim.x + threadIdx.x;
    const int n  = t >> 7;
    const int dq = (t & 127) * 4;
    const int ind = inds[n];
    const float4 xv = *(const float4*)(x + (size_t)n * DDIM + dq);
    const float4 ev = *(const float4*)(e + (size_t)ind * DDIM + dq);
    float4 o;
    o.x = __fadd_rn(xv.x, __fsub_rn(ev.x, xv.x));
    o.y = __fadd_rn(xv.y, __fsub_rn(ev.y, xv.y));
    o.z = __fadd_rn(xv.z, __fsub_rn(ev.z, xv.z));
    o.w = __fadd_rn(xv.w, __fsub_rn(ev.w, xv.w));
    *(float4*)(out + (size_t)n * DDIM + dq) = o;
}

extern "C" void kernel_launch(void* const* d_in, const int* in_sizes, int n_in,
                              void* d_out, int out_size, void* d_ws, size_t ws_size,
                              hipStream_t stream) {
    const float* lat = (const float*)d_in[0];   // (16,2048,512) fp32
    const float* emb = (const float*)d_in[1];   // (8192,512) fp32
    float* out = (float*)d_out;

    char* ws = (char*)d_ws;
    size_t off = 0;
    float*    sume  = (float*)(ws + off);    off += (size_t)KC * 4;
    float*    sumx  = (float*)(ws + off);    off += (size_t)NR * 4;
    float*    semax = (float*)(ws + off);    off += 256;
    float*    lmin  = (float*)(ws + off);    off += (size_t)NR * NTILE * 4;
    float*    l2nd  = (float*)(ws + off);    off += (size_t)NR * NTILE * 4;
    int*      lidx  = (int*)  (ws + off);    off += (size_t)NR * NTILE * 4;
    int*      inds  = (int*)  (ws + off);    off += (size_t)NR * 4;
    unsigned* xb    = (unsigned*)(ws + off); off += (size_t)NR * DDIM * 2;
    unsigned* ebT   = (unsigned*)(ws + off); off += (size_t)KC * DDIM * 2;

    lat_prep_kernel<<<NR / 32, 256, 0, stream>>>(lat, xb, sumx);
    emb_prep_kernel<<<KC / 32, 256, 0, stream>>>(emb, ebT, sume);
    semax_kernel<<<1, 256, 0, stream>>>(sume, semax);
    gemm_filter_kernel<<<(NR / 128) * NTILE, 256, 0, stream>>>(xb, ebT, sume, lmin, l2nd, lidx);
    rescore_kernel<<<NR / 4, 256, 0, stream>>>(lat, emb, sumx, sume, semax, lmin, l2nd, lidx, inds);
    writeout_kernel<<<(NR * DDIM / 4) / 256, 256, 0, stream>>>(lat, emb, inds, out);
}

// Round 8
// 756.630 us; speedup vs baseline: 1.1021x; 1.1021x over previous
//
#include <hip/hip_runtime.h>
#include <hip/hip_bf16.h>
#include <float.h>

#define NR    32768
#define DDIM  512
#define KC    8192
#define NTILE 64      // KC / 128 code-tiles

typedef __attribute__((ext_vector_type(8))) short short8;   // 8 bf16 = 4 VGPR
typedef __attribute__((ext_vector_type(4))) float f32x4;
typedef const __attribute__((address_space(1))) char gchar_t;
typedef __attribute__((address_space(3))) char lchar_t;

// pack two fp32 -> two bf16 (RNE) in one u32 (low word = first element)
__device__ inline unsigned cvt2(float a, float b) {
    __hip_bfloat162 h = __float22bfloat162_rn(float2{a, b});
    union { __hip_bfloat162 h; unsigned u; } v; v.h = h;
    return v.u;
}

// FUSED latents prep, LDS-staged (verified R7, rest -13 us): 32 rows/block.
//  phase1: coalesced fp32 reads -> bf16 granules staged in LDS (pad 33).
//  phase1b: rownorm per row -- chain BITWISE-IDENTICAL to all prior rounds.
//  phase2: xb written in 512 B-contiguous runs (no partial-line scatter).
// xb layout: granule (RB, og, r) at u32 RB*32768 + og*512 + r*4.
__global__ __launch_bounds__(256) void lat_prep_kernel(const float* __restrict__ src,
                                                       unsigned* __restrict__ xb,
                                                       float* __restrict__ sumx) {
    __shared__ uint4 st[64 * 33];            // [og][row], +1 pad granule
    const int t  = threadIdx.x;
    const int r0 = blockIdx.x * 32;          // first global row of this block

#pragma unroll
    for (int i = 0; i < 8; ++i) {
        const int u  = i * 256 + t;          // granule index in block
        const int rr = u >> 6;               // row 0..31
        const int og = u & 63;               // octet 0..63
        const float* p = src + (size_t)(r0 + rr) * DDIM + og * 8;
        const float4 a = *(const float4*)p;
        const float4 b = *(const float4*)(p + 4);
        uint4 v;
        v.x = cvt2(a.x, a.y); v.y = cvt2(a.z, a.w);
        v.z = cvt2(b.x, b.y); v.w = cvt2(b.z, b.w);
        st[og * 33 + rr] = v;
    }

    const int w = t >> 6, lane = t & 63;
#pragma unroll
    for (int s = 0; s < 8; ++s) {
        const int row = r0 + w * 8 + s;
        const float* p = src + (size_t)row * DDIM;
        float acc = 0.0f;
#pragma unroll
        for (int i = 0; i < DDIM / 64; ++i) {
            float v = p[lane + i * 64];
            acc = __builtin_fmaf(v, v, acc);
        }
#pragma unroll
        for (int off = 32; off > 0; off >>= 1) acc += __shfl_down(acc, off, 64);
        if (lane == 0) sumx[row] = acc;
    }
    __syncthreads();

    const int RB = r0 >> 7, rb = r0 & 127;
    uint4* xb4 = (uint4*)xb;
#pragma unroll
    for (int k = 0; k < 8; ++k) {
        const int u  = k * 256 + t;
        const int og = u >> 5, rr = u & 31;
        xb4[(size_t)RB * 8192 + og * 128 + rb + rr] = st[og * 33 + rr];
    }
}

// FUSED codebook prep, LDS-staged (verified R7): 32 rows/block.
// ebT layout: granule (g, k) at uint4 index g*8192 + k (fragment-major).
__global__ __launch_bounds__(256) void emb_prep_kernel(const float* __restrict__ src,
                                                       unsigned* __restrict__ ebT,
                                                       float* __restrict__ sume) {
    __shared__ uint4 st[64 * 33];
    const int t  = threadIdx.x;
    const int k0 = blockIdx.x * 32;

#pragma unroll
    for (int i = 0; i < 8; ++i) {
        const int u  = i * 256 + t;
        const int rr = u >> 6;
        const int g  = u & 63;
        const float* p = src + (size_t)(k0 + rr) * DDIM + g * 8;
        const float4 a = *(const float4*)p;
        const float4 b = *(const float4*)(p + 4);
        uint4 v;
        v.x = cvt2(a.x, a.y); v.y = cvt2(a.z, a.w);
        v.z = cvt2(b.x, b.y); v.w = cvt2(b.z, b.w);
        st[g * 33 + rr] = v;
    }

    const int w = t >> 6, lane = t & 63;
#pragma unroll
    for (int s = 0; s < 8; ++s) {
        const int k = k0 + w * 8 + s;
        const float* p = src + (size_t)k * DDIM;
        float acc = 0.0f;
#pragma unroll
        for (int i = 0; i < DDIM / 64; ++i) {
            float v = p[lane + i * 64];
            acc = __builtin_fmaf(v, v, acc);
        }
#pragma unroll
        for (int off = 32; off > 0; off >>= 1) acc += __shfl_down(acc, off, 64);
        if (lane == 0) sume[k] = acc;
    }
    __syncthreads();

    uint4* eb4 = (uint4*)ebT;
#pragma unroll
    for (int kk = 0; kk < 8; ++kk) {
        const int u  = kk * 256 + t;
        const int g  = u >> 5, rr = u & 31;
        eb4[(size_t)g * 8192 + k0 + rr] = st[g * 33 + rr];
    }
}

__global__ __launch_bounds__(256) void semax_kernel(const float* __restrict__ sume,
                                                    float* __restrict__ semax) {
    __shared__ float red[256];
    float m = 0.f;
    for (int i = threadIdx.x; i < KC; i += 256) m = fmaxf(m, sume[i]);
    red[threadIdx.x] = m;
    __syncthreads();
    for (int s = 128; s > 0; s >>= 1) {
        if (threadIdx.x < s) red[threadIdx.x] = fmaxf(red[threadIdx.x], red[threadIdx.x + s]);
        __syncthreads();
    }
    if (threadIdx.x == 0) semax[0] = sqrtf(red[0]);
}

// bf16 MFMA approx-score GEMM + per-(row, code-tile) (min, argmin, 2ndmin).
// Round-8 = verified R2/R6 tile (64x64 waves: 4 ds_read : 16 MFMA per iter --
// R7 proved the per-wave LDS-read path is the binding resource; DO NOT
// retile) + prefetch depth 2 -> 3 to cover X's ~900-cyc HBM latency:
//  * 4 LDS X-buffers (32 KB), 4 B register sets; group = 6 VMEM/iter
//    (2 X-DMA + 4 B); in-loop wait vmcnt(12) leaves TWO groups in flight
//    (was one). Drain: it=14 -> vmcnt(6), it=15 -> vmcnt(0).
//  * buffer liveness: buf (it+3)&3 == buf of tile it-1, whose LDS reads
//    completed before this iter's barrier -- same proof as depth-2.
//  * keep: octet-major xb (linear gload_lds, conflict-free 256 B A-reads),
//    implicit nb%8 XCD pinning (DO NOT remap -- R3: FETCH x4), stats
//    [nb][row] (512 B contiguous stores).
__global__ __launch_bounds__(256) void gemm_filter_kernel(
        const unsigned* __restrict__ xb, const unsigned* __restrict__ ebT,
        const float* __restrict__ sume,
        float* __restrict__ lmin, float* __restrict__ l2nd, int* __restrict__ lidx) {
    __shared__ alignas(16) char smem[32768];   // X 4 x 8 KB; epilogue overlay

    const int tid  = threadIdx.x;
    const int nb   = blockIdx.x & (NTILE - 1);
    const int mb   = blockIdx.x >> 6;
    const int row0 = mb * 128, col0 = nb * 128;
    const int lane = tid & 63, w = tid >> 6;
    const int wy = w >> 1, wx = w & 1;
    const int l15 = lane & 15, q4 = lane >> 4;   // q4 in [0,4)

    f32x4 acc[4][4];
#pragma unroll
    for (int i = 0; i < 4; ++i)
#pragma unroll
        for (int j = 0; j < 4; ++j) acc[i][j] = f32x4{0.f, 0.f, 0.f, 0.f};

    // X staging: region R = w*2+t, 1 KB linear per gload_lds (verbatim copy)
    const char* xg[2];
#pragma unroll
    for (int t = 0; t < 2; ++t)
        xg[t] = (const char*)xb + (size_t)mb * 131072 + ((w * 2 + t) << 10) + (lane << 4);
    // A-fragment byte offset in octet-major tile: o=q4, row=64*wy+16i+l15
    const int aoff = (q4 << 11) + ((64 * wy + l15) << 4);   // + i*256

    // B global base: granule (g = q4, col = col0 + 64wx + l15), u32 units
    const unsigned* bptr = ebT + ((size_t)(q4 * KC + col0 + 64 * wx + l15)) * 4;
    // j-stride: 16 cols = 64 u32; tile-stride: 4*KC granules = 131072 u32

    short8 B[4][4];

    // prologue: stage tiles 0,1,2 (X -> LDS bufs 0-2; B -> reg sets 0-2)
#pragma unroll
    for (int p = 0; p < 3; ++p) {
#pragma unroll
        for (int t = 0; t < 2; ++t)
            __builtin_amdgcn_global_load_lds((gchar_t*)(xg[t] + p * 8192),
                (lchar_t*)(smem + p * 8192 + ((w * 2 + t) << 10) + (lane << 4)), 16, 0, 0);
        const unsigned* bn = bptr + (size_t)p * 131072;
#pragma unroll
        for (int j = 0; j < 4; ++j) B[p][j] = *(const short8*)(bn + j * 64);
    }

#pragma unroll
    for (int it = 0; it < 16; ++it) {
        // Drain tile it's issue-group (6 VMEM); keep groups it+1, it+2 in
        // flight across the barrier (depth-3).
        if (it < 14)      asm volatile("s_waitcnt vmcnt(12)" ::: "memory");
        else if (it == 14) asm volatile("s_waitcnt vmcnt(6)" ::: "memory");
        else               asm volatile("s_waitcnt vmcnt(0)" ::: "memory");
        __builtin_amdgcn_sched_barrier(0);
        __builtin_amdgcn_s_barrier();
        __builtin_amdgcn_sched_barrier(0);
        // issue tile it+3: X into buf (it+3)&3 (= buf of tile it-1, released
        // by the barrier above), B into reg set (it+3)&3.
        if (it + 3 < 16) {
#pragma unroll
            for (int t = 0; t < 2; ++t)
                __builtin_amdgcn_global_load_lds((gchar_t*)(xg[t] + (it + 3) * 8192),
                    (lchar_t*)(smem + ((it + 3) & 3) * 8192 + ((w * 2 + t) << 10) + (lane << 4)), 16, 0, 0);
            const unsigned* bn = bptr + (size_t)(it + 3) * 131072;
#pragma unroll
            for (int j = 0; j < 4; ++j) B[(it + 3) & 3][j] = *(const short8*)(bn + j * 64);
        }
        __builtin_amdgcn_sched_barrier(0);
        // compute tile it
        const char* Xc = smem + (it & 3) * 8192;
        short8 A[4];
#pragma unroll
        for (int i = 0; i < 4; ++i)
            A[i] = *(const short8*)(Xc + aoff + i * 256);
#pragma unroll
        for (int i = 0; i < 4; ++i)
#pragma unroll
            for (int j = 0; j < 4; ++j)
                acc[i][j] = __builtin_amdgcn_mfma_f32_16x16x32_bf16(A[i], B[it & 3][j], acc[i][j], 0, 0, 0);
    }

    // ---- epilogue: per-row (min, argmin, 2ndmin) over this 128-code tile.
    float se[4];
#pragma unroll
    for (int j = 0; j < 4; ++j) se[j] = sume[col0 + 64 * wx + 16 * j + l15];

    __syncthreads();   // all waves done reading LDS before scratch overlays it
    float* pv1 = (float*)smem;             // [128][8]
    float* pv2 = (float*)(smem + 4096);    // [128][8]
    int*   pk1 = (int*)(smem + 8192);      // [128][8]

#pragma unroll
    for (int i = 0; i < 4; ++i) {
#pragma unroll
        for (int reg = 0; reg < 4; ++reg) {
            float v1 = FLT_MAX, v2 = FLT_MAX; int k1 = 0;
#pragma unroll
            for (int j = 0; j < 4; ++j) {
                const float s = __builtin_fmaf(-2.f, acc[i][j][reg], se[j]);
                const int c = col0 + 64 * wx + 16 * j + l15;
                if (s < v1) { v2 = v1; v1 = s; k1 = c; }
                else        { v2 = fminf(v2, s); }
            }
            // merge groups of 4 l15-lanes (exact ties leave l2nd==lmin -> the
            // rescore full-scans the tile, so tie-side argmin choice is moot)
#pragma unroll
            for (int m = 1; m <= 2; m <<= 1) {
                const float ov1 = __shfl_xor(v1, m, 64);
                const int   ok1 = __shfl_xor(k1, m, 64);
                const float ov2 = __shfl_xor(v2, m, 64);
                const float nv2 = fminf(fmaxf(v1, ov1), fminf(v2, ov2));
                if (ov1 < v1) { v1 = ov1; k1 = ok1; }
                v2 = nv2;
            }
            if ((l15 & 3) == 0) {
                const int rowl = 64 * wy + 16 * i + 4 * q4 + reg;
                const int c8   = wx * 4 + (l15 >> 2);
                const int slot = rowl * 8 + ((c8 + rowl) & 7);   // rotation swizzle
                pv1[slot] = v1; pv2[slot] = v2; pk1[slot] = k1;
            }
        }
    }
    __syncthreads();
    if (tid < 128) {
        float g1 = FLT_MAX, g2 = FLT_MAX; int gk = 0;
#pragma unroll
        for (int c = 0; c < 8; ++c) {
            const int slot = tid * 8 + ((c + tid) & 7);
            const float p1 = pv1[slot];
            const float p2 = pv2[slot];
            const int   pk = pk1[slot];
            if (p1 < g1) { g2 = fminf(g1, p2); g1 = p1; gk = pk; }
            else         { g2 = fminf(g2, p1); }
        }
        // transposed stat layout [nb][row]: 512 B contiguous per array
        const size_t o = (size_t)nb * NR + row0 + tid;
        lmin[o] = g1; l2nd[o] = g2; lidx[o] = gk;
    }
}

// exact rescore of provably-covering candidate set; one wave per row.
// margin = 2*(2^-7*||x||*||e||max + 6.5e-5): bf16-RNE dot error bound + two
// half-ulp(512) roundings in the exact formula, doubled for two-sidedness.
__global__ __launch_bounds__(256) void rescore_kernel(
        const float* __restrict__ x, const float* __restrict__ e,
        const float* __restrict__ sumx, const float* __restrict__ sume,
        const float* __restrict__ semax,
        const float* __restrict__ lmin, const float* __restrict__ l2nd,
        const int* __restrict__ lidx, int* __restrict__ inds) {
    __shared__ float xr[4][DDIM];
    __shared__ int list[4][64];

    const int w = threadIdx.x >> 6, lane = threadIdx.x & 63;
    const int row = blockIdx.x * 4 + w;

    // transposed stat layout [tile][row] (written coalesced by the gemm)
    const float lm = lmin[(size_t)lane * NR + row];
    const float l2 = l2nd[(size_t)lane * NR + row];
    const int   li = lidx[(size_t)lane * NR + row];

    float mr = lm;
#pragma unroll
    for (int m = 1; m < 64; m <<= 1) mr = fminf(mr, __shfl_xor(mr, m, 64));

    const float sx  = sumx[row];
    const float thr = mr + (0.0157f * sqrtf(sx) * semax[0] + 1.4e-4f);

    const bool single = (lm <= thr) && (l2 > thr);
    const unsigned long long bs = __ballot(single);
    const int pos = __popcll(bs & ((1ull << lane) - 1ull));
    if (single) list[w][pos] = li;
    const int nS = __popcll(bs);
    unsigned long long bf = __ballot(l2 <= thr);

    {
        const float* px = x + (size_t)row * DDIM + lane * 8;
        *(float4*)(&xr[w][lane * 8])     = *(const float4*)(px);
        *(float4*)(&xr[w][lane * 8 + 4]) = *(const float4*)(px + 4);
    }
    __syncthreads();

    float bd = FLT_MAX; int bk = 0x7fffffff;
    // exact dist: float4 loads, FMA order identical to all prior rounds
#define EVAL(KK)                                                             \
    {                                                                        \
        const int k_ = (KK);                                                 \
        const float4* ep4 = (const float4*)(e + ((size_t)k_ << 9));          \
        float dot = 0.f;                                                     \
        _Pragma("unroll 4")                                                  \
        for (int d4 = 0; d4 < 128; ++d4) {                                   \
            const float4 ev = ep4[d4];                                       \
            const float4 xv = *(const float4*)(&xr[w][d4 * 4]);              \
            dot = __builtin_fmaf(xv.x, ev.x, dot);                           \
            dot = __builtin_fmaf(xv.y, ev.y, dot);                           \
            dot = __builtin_fmaf(xv.z, ev.z, dot);                           \
            dot = __builtin_fmaf(xv.w, ev.w, dot);                           \
        }                                                                    \
        const float t1   = __fadd_rn(sx, sume[k_]);                          \
        const float dist = __fsub_rn(t1, __fadd_rn(dot, dot));               \
        if (dist < bd || (dist == bd && k_ < bk)) { bd = dist; bk = k_; }    \
    }

    if (lane < nS) EVAL(list[w][lane]);
    while (bf) {
        const int t = __ffsll((long long)bf) - 1;
        bf &= bf - 1;
        EVAL(128 * t + lane);
        EVAL(128 * t + 64 + lane);
    }
#undef EVAL

#pragma unroll
    for (int m = 1; m < 64; m <<= 1) {
        const float od = __shfl_xor(bd, m, 64);
        const int   ok = __shfl_xor(bk, m, 64);
        if (od < bd || (od == bd && ok < bk)) { bd = od; bk = ok; }
    }
    if (lane == 0) inds[row] = bk;
}

// out = x + (e[ind] - x), exact elementwise fp32 STE
__global__ __launch_bounds__(256) void writeout_kernel(const float* __restrict__ x,
                                                       const float* __restrict__ e,
                                                       const int* __restrict__ inds,
                                                       float* __restrict__ out) {
    const int t  = blockIdx.x * blockDim.x + threadIdx.x;
    const int n  = t >> 7;
    const int dq = (t & 127) * 4;
    const int ind = inds[n];
    const float4 xv = *(const float4*)(x + (size_t)n * DDIM + dq);
    const float4 ev = *(const float4*)(e + (size_t)ind * DDIM + dq);
    float4 o;
    o.x = __fadd_rn(xv.x, __fsub_rn(ev.x, xv.x));
    o.y = __fadd_rn(xv.y, __fsub_rn(ev.y, xv.y));
    o.z = __fadd_rn(xv.z, __fsub_rn(ev.z, xv.z));
    o.w = __fadd_rn(xv.w, __fsub_rn(ev.w, xv.w));
    *(float4*)(out + (size_t)n * DDIM + dq) = o;
}

extern "C" void kernel_launch(void* const* d_in, const int* in_sizes, int n_in,
                              void* d_out, int out_size, void* d_ws, size_t ws_size,
                              hipStream_t stream) {
    const float* lat = (const float*)d_in[0];   // (16,2048,512) fp32
    const float* emb = (const float*)d_in[1];   // (8192,512) fp32
    float* out = (float*)d_out;

    char* ws = (char*)d_ws;
    size_t off = 0;
    float*    sume  = (float*)(ws + off);    off += (size_t)KC * 4;
    float*    sumx  = (float*)(ws + off);    off += (size_t)NR * 4;
    float*    semax = (float*)(ws + off);    off += 256;
    float*    lmin  = (float*)(ws + off);    off += (size_t)NR * NTILE * 4;
    float*    l2nd  = (float*)(ws + off);    off += (size_t)NR * NTILE * 4;
    int*      lidx  = (int*)  (ws + off);    off += (size_t)NR * NTILE * 4;
    int*      inds  = (int*)  (ws + off);    off += (size_t)NR * 4;
    unsigned* xb    = (unsigned*)(ws + off); off += (size_t)NR * DDIM * 2;
    unsigned* ebT   = (unsigned*)(ws + off); off += (size_t)KC * DDIM * 2;

    lat_prep_kernel<<<NR / 32, 256, 0, stream>>>(lat, xb, sumx);
    emb_prep_kernel<<<KC / 32, 256, 0, stream>>>(emb, ebT, sume);
    semax_kernel<<<1, 256, 0, stream>>>(sume, semax);
    gemm_filter_kernel<<<(NR / 128) * NTILE, 256, 0, stream>>>(xb, ebT, sume, lmin, l2nd, lidx);
    rescore_kernel<<<NR / 4, 256, 0, stream>>>(lat, emb, sumx, sume, semax, lmin, l2nd, lidx, inds);
    writeout_kernel<<<(NR * DDIM / 4) / 256, 256, 0, stream>>>(lat, emb, inds, out);
}

// Round 9
// 712.329 us; speedup vs baseline: 1.1707x; 1.0622x over previous
//
#include <hip/hip_runtime.h>
#include <hip/hip_bf16.h>
#include <float.h>

#define NR    32768
#define DDIM  512
#define KC    8192
#define NTILE 64      // KC / 128 code-tiles

typedef __attribute__((ext_vector_type(8))) short short8;   // 8 bf16 = 4 VGPR
typedef __attribute__((ext_vector_type(4))) float f32x4;
typedef const __attribute__((address_space(1))) char gchar_t;
typedef __attribute__((address_space(3))) char lchar_t;

// pack two fp32 -> two bf16 (RNE) in one u32 (low word = first element)
__device__ inline unsigned cvt2(float a, float b) {
    __hip_bfloat162 h = __float22bfloat162_rn(float2{a, b});
    union { __hip_bfloat162 h; unsigned u; } v; v.h = h;
    return v.u;
}

// FUSED latents prep, LDS-staged (verified R7/R8, rest -13 us vs scatter):
// 32 rows/block. phase1: coalesced fp32 reads -> bf16 granules in LDS
// (pad 33). phase1b: rownorm -- chain BITWISE-IDENTICAL to all prior rounds.
// phase2: xb written in 512 B-contiguous runs (no partial-line scatter).
// xb layout: granule (RB, og, r) at u32 RB*32768 + og*512 + r*4.
__global__ __launch_bounds__(256) void lat_prep_kernel(const float* __restrict__ src,
                                                       unsigned* __restrict__ xb,
                                                       float* __restrict__ sumx) {
    __shared__ uint4 st[64 * 33];            // [og][row], +1 pad granule
    const int t  = threadIdx.x;
    const int r0 = blockIdx.x * 32;          // first global row of this block

#pragma unroll
    for (int i = 0; i < 8; ++i) {
        const int u  = i * 256 + t;          // granule index in block
        const int rr = u >> 6;               // row 0..31
        const int og = u & 63;               // octet 0..63
        const float* p = src + (size_t)(r0 + rr) * DDIM + og * 8;
        const float4 a = *(const float4*)p;
        const float4 b = *(const float4*)(p + 4);
        uint4 v;
        v.x = cvt2(a.x, a.y); v.y = cvt2(a.z, a.w);
        v.z = cvt2(b.x, b.y); v.w = cvt2(b.z, b.w);
        st[og * 33 + rr] = v;
    }

    const int w = t >> 6, lane = t & 63;
#pragma unroll
    for (int s = 0; s < 8; ++s) {
        const int row = r0 + w * 8 + s;
        const float* p = src + (size_t)row * DDIM;
        float acc = 0.0f;
#pragma unroll
        for (int i = 0; i < DDIM / 64; ++i) {
            float v = p[lane + i * 64];
            acc = __builtin_fmaf(v, v, acc);
        }
#pragma unroll
        for (int off = 32; off > 0; off >>= 1) acc += __shfl_down(acc, off, 64);
        if (lane == 0) sumx[row] = acc;
    }
    __syncthreads();

    const int RB = r0 >> 7, rb = r0 & 127;
    uint4* xb4 = (uint4*)xb;
#pragma unroll
    for (int k = 0; k < 8; ++k) {
        const int u  = k * 256 + t;
        const int og = u >> 5, rr = u & 31;
        xb4[(size_t)RB * 8192 + og * 128 + rb + rr] = st[og * 33 + rr];
    }
}

// FUSED codebook prep, LDS-staged (verified R7/R8): 32 rows/block.
// ebT layout: granule (g, k) at uint4 index g*8192 + k (fragment-major).
__global__ __launch_bounds__(256) void emb_prep_kernel(const float* __restrict__ src,
                                                       unsigned* __restrict__ ebT,
                                                       float* __restrict__ sume) {
    __shared__ uint4 st[64 * 33];
    const int t  = threadIdx.x;
    const int k0 = blockIdx.x * 32;

#pragma unroll
    for (int i = 0; i < 8; ++i) {
        const int u  = i * 256 + t;
        const int rr = u >> 6;
        const int g  = u & 63;
        const float* p = src + (size_t)(k0 + rr) * DDIM + g * 8;
        const float4 a = *(const float4*)p;
        const float4 b = *(const float4*)(p + 4);
        uint4 v;
        v.x = cvt2(a.x, a.y); v.y = cvt2(a.z, a.w);
        v.z = cvt2(b.x, b.y); v.w = cvt2(b.z, b.w);
        st[g * 33 + rr] = v;
    }

    const int w = t >> 6, lane = t & 63;
#pragma unroll
    for (int s = 0; s < 8; ++s) {
        const int k = k0 + w * 8 + s;
        const float* p = src + (size_t)k * DDIM;
        float acc = 0.0f;
#pragma unroll
        for (int i = 0; i < DDIM / 64; ++i) {
            float v = p[lane + i * 64];
            acc = __builtin_fmaf(v, v, acc);
        }
#pragma unroll
        for (int off = 32; off > 0; off >>= 1) acc += __shfl_down(acc, off, 64);
        if (lane == 0) sume[k] = acc;
    }
    __syncthreads();

    uint4* eb4 = (uint4*)ebT;
#pragma unroll
    for (int kk = 0; kk < 8; ++kk) {
        const int u  = kk * 256 + t;
        const int g  = u >> 5, rr = u & 31;
        eb4[(size_t)g * 8192 + k0 + rr] = st[g * 33 + rr];
    }
}

__global__ __launch_bounds__(256) void semax_kernel(const float* __restrict__ sume,
                                                    float* __restrict__ semax) {
    __shared__ float red[256];
    float m = 0.f;
    for (int i = threadIdx.x; i < KC; i += 256) m = fmaxf(m, sume[i]);
    red[threadIdx.x] = m;
    __syncthreads();
    for (int s = 128; s > 0; s >>= 1) {
        if (threadIdx.x < s) red[threadIdx.x] = fmaxf(red[threadIdx.x], red[threadIdx.x + s]);
        __syncthreads();
    }
    if (threadIdx.x == 0) semax[0] = sqrtf(red[0]);
}

// bf16 MFMA approx-score GEMM + per-(row, code-tile) (min, argmin, 2ndmin).
// The verified R2/R5/R6 structure EXACTLY (327.4 us, 3 confirmations).
// Tested-and-rejected departures (DO NOT revisit):
//  * 256x256 tile (R3): occupancy+cache thrash, 388 us
//  * XCD-chunked remap (R3): FETCH 135->541 MB
//  * 128x32 wave retile (R7): per-wave LDS-read path binds, 458 us
//  * depth-3 prefetch (R8): occupancy 32->22%, 397 us
// Binding resource at 327 us: 2-phase structure's barrier cadence with
// ~10 waves/CU inter-block overlap (MfmaUtil 39%, no pipe saturated) --
// the documented 2-phase-template ceiling.
__global__ __launch_bounds__(256) void gemm_filter_kernel(
        const unsigned* __restrict__ xb, const unsigned* __restrict__ ebT,
        const float* __restrict__ sume,
        float* __restrict__ lmin, float* __restrict__ l2nd, int* __restrict__ lidx) {
    __shared__ alignas(16) char smem[24576];   // X 3 x 8 KB; epilogue overlay

    const int tid  = threadIdx.x;
    const int nb   = blockIdx.x & (NTILE - 1);
    const int mb   = blockIdx.x >> 6;
    const int row0 = mb * 128, col0 = nb * 128;
    const int lane = tid & 63, w = tid >> 6;
    const int wy = w >> 1, wx = w & 1;
    const int l15 = lane & 15, q4 = lane >> 4;   // q4 in [0,4)

    f32x4 acc[4][4];
#pragma unroll
    for (int i = 0; i < 4; ++i)
#pragma unroll
        for (int j = 0; j < 4; ++j) acc[i][j] = f32x4{0.f, 0.f, 0.f, 0.f};

    // X staging: region R = w*2+t, 1 KB linear per gload_lds (verbatim copy)
    const char* xg[2];
#pragma unroll
    for (int t = 0; t < 2; ++t)
        xg[t] = (const char*)xb + (size_t)mb * 131072 + ((w * 2 + t) << 10) + (lane << 4);
    // A-fragment byte offset in octet-major tile: o=q4, row=64*wy+16i+l15
    const int aoff = (q4 << 11) + ((64 * wy + l15) << 4);   // + i*256

    // B global base: granule (g = q4, col = col0 + 64wx + l15), u32 units
    const unsigned* bptr = ebT + ((size_t)(q4 * KC + col0 + 64 * wx + l15)) * 4;
    // j-stride: 16 cols = 64 u32; tile-stride: 4*KC granules = 131072 u32

    short8 B[3][4];

    // prologue: stage tiles 0,1 (X -> LDS bufs 0,1; B -> reg sets 0,1)
#pragma unroll
    for (int p = 0; p < 2; ++p) {
#pragma unroll
        for (int t = 0; t < 2; ++t)
            __builtin_amdgcn_global_load_lds((gchar_t*)(xg[t] + p * 8192),
                (lchar_t*)(smem + p * 8192 + ((w * 2 + t) << 10) + (lane << 4)), 16, 0, 0);
        const unsigned* bn = bptr + (size_t)p * 131072;
#pragma unroll
        for (int j = 0; j < 4; ++j) B[p][j] = *(const short8*)(bn + j * 64);
    }

#pragma unroll
    for (int it = 0; it < 16; ++it) {
        // Drain whole issue-group of tile `it` (6 VMEM: 2 X-DMA + 4 B),
        // keep tile it+1's group (6) in flight across the barrier.
        if (it < 15) asm volatile("s_waitcnt vmcnt(6)" ::: "memory");
        else         asm volatile("s_waitcnt vmcnt(0)" ::: "memory");
        __builtin_amdgcn_sched_barrier(0);
        __builtin_amdgcn_s_barrier();
        __builtin_amdgcn_sched_barrier(0);
        // issue tile it+2: X into buf (it+2)%3 (= buf (it-1)%3, released by
        // the barrier above), B into reg set (it+2)%3.
        if (it + 2 < 16) {
#pragma unroll
            for (int t = 0; t < 2; ++t)
                __builtin_amdgcn_global_load_lds((gchar_t*)(xg[t] + (it + 2) * 8192),
                    (lchar_t*)(smem + ((it + 2) % 3) * 8192 + ((w * 2 + t) << 10) + (lane << 4)), 16, 0, 0);
            const unsigned* bn = bptr + (size_t)(it + 2) * 131072;
#pragma unroll
            for (int j = 0; j < 4; ++j) B[(it + 2) % 3][j] = *(const short8*)(bn + j * 64);
        }
        __builtin_amdgcn_sched_barrier(0);
        // compute tile it
        const char* Xc = smem + (it % 3) * 8192;
        short8 A[4];
#pragma unroll
        for (int i = 0; i < 4; ++i)
            A[i] = *(const short8*)(Xc + aoff + i * 256);
#pragma unroll
        for (int i = 0; i < 4; ++i)
#pragma unroll
            for (int j = 0; j < 4; ++j)
                acc[i][j] = __builtin_amdgcn_mfma_f32_16x16x32_bf16(A[i], B[it % 3][j], acc[i][j], 0, 0, 0);
    }

    // ---- epilogue: per-row (min, argmin, 2ndmin) over this 128-code tile.
    float se[4];
#pragma unroll
    for (int j = 0; j < 4; ++j) se[j] = sume[col0 + 64 * wx + 16 * j + l15];

    __syncthreads();   // all waves done reading LDS before scratch overlays it
    float* pv1 = (float*)smem;             // [128][8]
    float* pv2 = (float*)(smem + 4096);    // [128][8]
    int*   pk1 = (int*)(smem + 8192);      // [128][8]

#pragma unroll
    for (int i = 0; i < 4; ++i) {
#pragma unroll
        for (int reg = 0; reg < 4; ++reg) {
            float v1 = FLT_MAX, v2 = FLT_MAX; int k1 = 0;
#pragma unroll
            for (int j = 0; j < 4; ++j) {
                const float s = __builtin_fmaf(-2.f, acc[i][j][reg], se[j]);
                const int c = col0 + 64 * wx + 16 * j + l15;
                if (s < v1) { v2 = v1; v1 = s; k1 = c; }
                else        { v2 = fminf(v2, s); }
            }
            // merge groups of 4 l15-lanes (exact ties leave l2nd==lmin -> the
            // rescore full-scans the tile, so tie-side argmin choice is moot)
#pragma unroll
            for (int m = 1; m <= 2; m <<= 1) {
                const float ov1 = __shfl_xor(v1, m, 64);
                const int   ok1 = __shfl_xor(k1, m, 64);
                const float ov2 = __shfl_xor(v2, m, 64);
                const float nv2 = fminf(fmaxf(v1, ov1), fminf(v2, ov2));
                if (ov1 < v1) { v1 = ov1; k1 = ok1; }
                v2 = nv2;
            }
            if ((l15 & 3) == 0) {
                const int rowl = 64 * wy + 16 * i + 4 * q4 + reg;
                const int c8   = wx * 4 + (l15 >> 2);
                const int slot = rowl * 8 + ((c8 + rowl) & 7);   // rotation swizzle
                pv1[slot] = v1; pv2[slot] = v2; pk1[slot] = k1;
            }
        }
    }
    __syncthreads();
    if (tid < 128) {
        float g1 = FLT_MAX, g2 = FLT_MAX; int gk = 0;
#pragma unroll
        for (int c = 0; c < 8; ++c) {
            const int slot = tid * 8 + ((c + tid) & 7);
            const float p1 = pv1[slot];
            const float p2 = pv2[slot];
            const int   pk = pk1[slot];
            if (p1 < g1) { g2 = fminf(g1, p2); g1 = p1; gk = pk; }
            else         { g2 = fminf(g2, p1); }
        }
        // transposed stat layout [nb][row]: 512 B contiguous per array
        const size_t o = (size_t)nb * NR + row0 + tid;
        lmin[o] = g1; l2nd[o] = g2; lidx[o] = gk;
    }
}

// exact rescore of provably-covering candidate set; one wave per row.
// margin = 2*(2^-7*||x||*||e||max + 6.5e-5): bf16-RNE dot error bound + two
// half-ulp(512) roundings in the exact formula, doubled for two-sidedness.
__global__ __launch_bounds__(256) void rescore_kernel(
        const float* __restrict__ x, const float* __restrict__ e,
        const float* __restrict__ sumx, const float* __restrict__ sume,
        const float* __restrict__ semax,
        const float* __restrict__ lmin, const float* __restrict__ l2nd,
        const int* __restrict__ lidx, int* __restrict__ inds) {
    __shared__ float xr[4][DDIM];
    __shared__ int list[4][64];

    const int w = threadIdx.x >> 6, lane = threadIdx.x & 63;
    const int row = blockIdx.x * 4 + w;

    // transposed stat layout [tile][row] (written coalesced by the gemm)
    const float lm = lmin[(size_t)lane * NR + row];
    const float l2 = l2nd[(size_t)lane * NR + row];
    const int   li = lidx[(size_t)lane * NR + row];

    float mr = lm;
#pragma unroll
    for (int m = 1; m < 64; m <<= 1) mr = fminf(mr, __shfl_xor(mr, m, 64));

    const float sx  = sumx[row];
    const float thr = mr + (0.0157f * sqrtf(sx) * semax[0] + 1.4e-4f);

    const bool single = (lm <= thr) && (l2 > thr);
    const unsigned long long bs = __ballot(single);
    const int pos = __popcll(bs & ((1ull << lane) - 1ull));
    if (single) list[w][pos] = li;
    const int nS = __popcll(bs);
    unsigned long long bf = __ballot(l2 <= thr);

    {
        const float* px = x + (size_t)row * DDIM + lane * 8;
        *(float4*)(&xr[w][lane * 8])     = *(const float4*)(px);
        *(float4*)(&xr[w][lane * 8 + 4]) = *(const float4*)(px + 4);
    }
    __syncthreads();

    float bd = FLT_MAX; int bk = 0x7fffffff;
    // exact dist: float4 loads, FMA order identical to all prior rounds
#define EVAL(KK)                                                             \
    {                                                                        \
        const int k_ = (KK);                                                 \
        const float4* ep4 = (const float4*)(e + ((size_t)k_ << 9));          \
        float dot = 0.f;                                                     \
        _Pragma("unroll 4")                                                  \
        for (int d4 = 0; d4 < 128; ++d4) {                                   \
            const float4 ev = ep4[d4];                                       \
            const float4 xv = *(const float4*)(&xr[w][d4 * 4]);              \
            dot = __builtin_fmaf(xv.x, ev.x, dot);                           \
            dot = __builtin_fmaf(xv.y, ev.y, dot);                           \
            dot = __builtin_fmaf(xv.z, ev.z, dot);                           \
            dot = __builtin_fmaf(xv.w, ev.w, dot);                           \
        }                                                                    \
        const float t1   = __fadd_rn(sx, sume[k_]);                          \
        const float dist = __fsub_rn(t1, __fadd_rn(dot, dot));               \
        if (dist < bd || (dist == bd && k_ < bk)) { bd = dist; bk = k_; }    \
    }

    if (lane < nS) EVAL(list[w][lane]);
    while (bf) {
        const int t = __ffsll((long long)bf) - 1;
        bf &= bf - 1;
        EVAL(128 * t + lane);
        EVAL(128 * t + 64 + lane);
    }
#undef EVAL

#pragma unroll
    for (int m = 1; m < 64; m <<= 1) {
        const float od = __shfl_xor(bd, m, 64);
        const int   ok = __shfl_xor(bk, m, 64);
        if (od < bd || (od == bd && ok < bk)) { bd = od; bk = ok; }
    }
    if (lane == 0) inds[row] = bk;
}

// out = x + (e[ind] - x), exact elementwise fp32 STE
__global__ __launch_bounds__(256) void writeout_kernel(const float* __restrict__ x,
                                                       const float* __restrict__ e,
                                                       const int* __restrict__ inds,
                                                       float* __restrict__ out) {
    const int t  = blockIdx.x * blockDim.x + threadIdx.x;
    const int n  = t >> 7;
    const int dq = (t & 127) * 4;
    const int ind = inds[n];
    const float4 xv = *(const float4*)(x + (size_t)n * DDIM + dq);
    const float4 ev = *(const float4*)(e + (size_t)ind * DDIM + dq);
    float4 o;
    o.x = __fadd_rn(xv.x, __fsub_rn(ev.x, xv.x));
    o.y = __fadd_rn(xv.y, __fsub_rn(ev.y, xv.y));
    o.z = __fadd_rn(xv.z, __fsub_rn(ev.z, xv.z));
    o.w = __fadd_rn(xv.w, __fsub_rn(ev.w, xv.w));
    *(float4*)(out + (size_t)n * DDIM + dq) = o;
}

extern "C" void kernel_launch(void* const* d_in, const int* in_sizes, int n_in,
                              void* d_out, int out_size, void* d_ws, size_t ws_size,
                              hipStream_t stream) {
    const float* lat = (const float*)d_in[0];   // (16,2048,512) fp32
    const float* emb = (const float*)d_in[1];   // (8192,512) fp32
    float* out = (float*)d_out;

    char* ws = (char*)d_ws;
    size_t off = 0;
    float*    sume  = (float*)(ws + off);    off += (size_t)KC * 4;
    float*    sumx  = (float*)(ws + off);    off += (size_t)NR * 4;
    float*    semax = (float*)(ws + off);    off += 256;
    float*    lmin  = (float*)(ws + off);    off += (size_t)NR * NTILE * 4;
    float*    l2nd  = (float*)(ws + off);    off += (size_t)NR * NTILE * 4;
    int*      lidx  = (int*)  (ws + off);    off += (size_t)NR * NTILE * 4;
    int*      inds  = (int*)  (ws + off);    off += (size_t)NR * 4;
    unsigned* xb    = (unsigned*)(ws + off); off += (size_t)NR * DDIM * 2;
    unsigned* ebT   = (unsigned*)(ws + off); off += (size_t)KC * DDIM * 2;

    lat_prep_kernel<<<NR / 32, 256, 0, stream>>>(lat, xb, sumx);
    emb_prep_kernel<<<KC / 32, 256, 0, stream>>>(emb, ebT, sume);
    semax_kernel<<<1, 256, 0, stream>>>(sume, semax);
    gemm_filter_kernel<<<(NR / 128) * NTILE, 256, 0, stream>>>(xb, ebT, sume, lmin, l2nd, lidx);
    rescore_kernel<<<NR / 4, 256, 0, stream>>>(lat, emb, sumx, sume, semax, lmin, l2nd, lidx, inds);
    writeout_kernel<<<(NR * DDIM / 4) / 256, 256, 0, stream>>>(lat, emb, inds, out);
}

// Round 10
// 679.509 us; speedup vs baseline: 1.2272x; 1.0483x over previous
//
#include <hip/hip_runtime.h>
#include <hip/hip_bf16.h>
#include <float.h>

#define NR    32768
#define DDIM  512
#define KC    8192
#define NTILE 64      // KC / 128 code-tiles

typedef __attribute__((ext_vector_type(8))) short short8;   // 8 bf16 = 4 VGPR
typedef __attribute__((ext_vector_type(4))) float f32x4;
typedef const __attribute__((address_space(1))) char gchar_t;
typedef __attribute__((address_space(3))) char lchar_t;

// pack two fp32 -> two bf16 (RNE) in one u32 (low word = first element)
__device__ inline unsigned cvt2(float a, float b) {
    __hip_bfloat162 h = __float22bfloat162_rn(float2{a, b});
    union { __hip_bfloat162 h; unsigned u; } v; v.h = h;
    return v.u;
}

// FUSED latents prep, LDS-staged (verified R7-R9): 32 rows/block.
// xb layout: granule (RB, og, r) at u32 RB*32768 + og*512 + r*4.
__global__ __launch_bounds__(256) void lat_prep_kernel(const float* __restrict__ src,
                                                       unsigned* __restrict__ xb,
                                                       float* __restrict__ sumx) {
    __shared__ uint4 st[64 * 33];            // [og][row], +1 pad granule
    const int t  = threadIdx.x;
    const int r0 = blockIdx.x * 32;          // first global row of this block

#pragma unroll
    for (int i = 0; i < 8; ++i) {
        const int u  = i * 256 + t;          // granule index in block
        const int rr = u >> 6;               // row 0..31
        const int og = u & 63;               // octet 0..63
        const float* p = src + (size_t)(r0 + rr) * DDIM + og * 8;
        const float4 a = *(const float4*)p;
        const float4 b = *(const float4*)(p + 4);
        uint4 v;
        v.x = cvt2(a.x, a.y); v.y = cvt2(a.z, a.w);
        v.z = cvt2(b.x, b.y); v.w = cvt2(b.z, b.w);
        st[og * 33 + rr] = v;
    }

    const int w = t >> 6, lane = t & 63;
#pragma unroll
    for (int s = 0; s < 8; ++s) {
        const int row = r0 + w * 8 + s;
        const float* p = src + (size_t)row * DDIM;
        float acc = 0.0f;
#pragma unroll
        for (int i = 0; i < DDIM / 64; ++i) {
            float v = p[lane + i * 64];
            acc = __builtin_fmaf(v, v, acc);
        }
#pragma unroll
        for (int off = 32; off > 0; off >>= 1) acc += __shfl_down(acc, off, 64);
        if (lane == 0) sumx[row] = acc;
    }
    __syncthreads();

    const int RB = r0 >> 7, rb = r0 & 127;
    uint4* xb4 = (uint4*)xb;
#pragma unroll
    for (int k = 0; k < 8; ++k) {
        const int u  = k * 256 + t;
        const int og = u >> 5, rr = u & 31;
        xb4[(size_t)RB * 8192 + og * 128 + rb + rr] = st[og * 33 + rr];
    }
}

// FUSED codebook prep, LDS-staged (verified R7-R9): 32 rows/block.
// ebT layout: granule (g, k) at uint4 index g*8192 + k (fragment-major).
__global__ __launch_bounds__(256) void emb_prep_kernel(const float* __restrict__ src,
                                                       unsigned* __restrict__ ebT,
                                                       float* __restrict__ sume) {
    __shared__ uint4 st[64 * 33];
    const int t  = threadIdx.x;
    const int k0 = blockIdx.x * 32;

#pragma unroll
    for (int i = 0; i < 8; ++i) {
        const int u  = i * 256 + t;
        const int rr = u >> 6;
        const int g  = u & 63;
        const float* p = src + (size_t)(k0 + rr) * DDIM + g * 8;
        const float4 a = *(const float4*)p;
        const float4 b = *(const float4*)(p + 4);
        uint4 v;
        v.x = cvt2(a.x, a.y); v.y = cvt2(a.z, a.w);
        v.z = cvt2(b.x, b.y); v.w = cvt2(b.z, b.w);
        st[g * 33 + rr] = v;
    }

    const int w = t >> 6, lane = t & 63;
#pragma unroll
    for (int s = 0; s < 8; ++s) {
        const int k = k0 + w * 8 + s;
        const float* p = src + (size_t)k * DDIM;
        float acc = 0.0f;
#pragma unroll
        for (int i = 0; i < DDIM / 64; ++i) {
            float v = p[lane + i * 64];
            acc = __builtin_fmaf(v, v, acc);
        }
#pragma unroll
        for (int off = 32; off > 0; off >>= 1) acc += __shfl_down(acc, off, 64);
        if (lane == 0) sume[k] = acc;
    }
    __syncthreads();

    uint4* eb4 = (uint4*)ebT;
#pragma unroll
    for (int kk = 0; kk < 8; ++kk) {
        const int u  = kk * 256 + t;
        const int g  = u >> 5, rr = u & 31;
        eb4[(size_t)g * 8192 + k0 + rr] = st[g * 33 + rr];
    }
}

__global__ __launch_bounds__(256) void semax_kernel(const float* __restrict__ sume,
                                                    float* __restrict__ semax) {
    __shared__ float red[256];
    float m = 0.f;
    for (int i = threadIdx.x; i < KC; i += 256) m = fmaxf(m, sume[i]);
    red[threadIdx.x] = m;
    __syncthreads();
    for (int s = 128; s > 0; s >>= 1) {
        if (threadIdx.x < s) red[threadIdx.x] = fmaxf(red[threadIdx.x], red[threadIdx.x + s]);
        __syncthreads();
    }
    if (threadIdx.x == 0) semax[0] = sqrtf(red[0]);
}

// bf16 MFMA approx-score GEMM + per-(row, code-tile) (min, argmin, 2ndmin).
// The verified R2/R5/R6/R9 structure EXACTLY (327-334 us, 4 confirmations).
// Tested-and-rejected departures (DO NOT revisit):
//  * 256x256 tile (R3) / XCD remap (R3) / 128x32 waves (R7) / depth-3 (R8).
__global__ __launch_bounds__(256) void gemm_filter_kernel(
        const unsigned* __restrict__ xb, const unsigned* __restrict__ ebT,
        const float* __restrict__ sume,
        float* __restrict__ lmin, float* __restrict__ l2nd, int* __restrict__ lidx) {
    __shared__ alignas(16) char smem[24576];   // X 3 x 8 KB; epilogue overlay

    const int tid  = threadIdx.x;
    const int nb   = blockIdx.x & (NTILE - 1);
    const int mb   = blockIdx.x >> 6;
    const int row0 = mb * 128, col0 = nb * 128;
    const int lane = tid & 63, w = tid >> 6;
    const int wy = w >> 1, wx = w & 1;
    const int l15 = lane & 15, q4 = lane >> 4;   // q4 in [0,4)

    f32x4 acc[4][4];
#pragma unroll
    for (int i = 0; i < 4; ++i)
#pragma unroll
        for (int j = 0; j < 4; ++j) acc[i][j] = f32x4{0.f, 0.f, 0.f, 0.f};

    // X staging: region R = w*2+t, 1 KB linear per gload_lds (verbatim copy)
    const char* xg[2];
#pragma unroll
    for (int t = 0; t < 2; ++t)
        xg[t] = (const char*)xb + (size_t)mb * 131072 + ((w * 2 + t) << 10) + (lane << 4);
    // A-fragment byte offset in octet-major tile: o=q4, row=64*wy+16i+l15
    const int aoff = (q4 << 11) + ((64 * wy + l15) << 4);   // + i*256

    // B global base: granule (g = q4, col = col0 + 64wx + l15), u32 units
    const unsigned* bptr = ebT + ((size_t)(q4 * KC + col0 + 64 * wx + l15)) * 4;

    short8 B[3][4];

    // prologue: stage tiles 0,1 (X -> LDS bufs 0,1; B -> reg sets 0,1)
#pragma unroll
    for (int p = 0; p < 2; ++p) {
#pragma unroll
        for (int t = 0; t < 2; ++t)
            __builtin_amdgcn_global_load_lds((gchar_t*)(xg[t] + p * 8192),
                (lchar_t*)(smem + p * 8192 + ((w * 2 + t) << 10) + (lane << 4)), 16, 0, 0);
        const unsigned* bn = bptr + (size_t)p * 131072;
#pragma unroll
        for (int j = 0; j < 4; ++j) B[p][j] = *(const short8*)(bn + j * 64);
    }

#pragma unroll
    for (int it = 0; it < 16; ++it) {
        // Drain whole issue-group of tile `it` (6 VMEM: 2 X-DMA + 4 B),
        // keep tile it+1's group (6) in flight across the barrier.
        if (it < 15) asm volatile("s_waitcnt vmcnt(6)" ::: "memory");
        else         asm volatile("s_waitcnt vmcnt(0)" ::: "memory");
        __builtin_amdgcn_sched_barrier(0);
        __builtin_amdgcn_s_barrier();
        __builtin_amdgcn_sched_barrier(0);
        // issue tile it+2: X into buf (it+2)%3 (= buf (it-1)%3, released by
        // the barrier above), B into reg set (it+2)%3.
        if (it + 2 < 16) {
#pragma unroll
            for (int t = 0; t < 2; ++t)
                __builtin_amdgcn_global_load_lds((gchar_t*)(xg[t] + (it + 2) * 8192),
                    (lchar_t*)(smem + ((it + 2) % 3) * 8192 + ((w * 2 + t) << 10) + (lane << 4)), 16, 0, 0);
            const unsigned* bn = bptr + (size_t)(it + 2) * 131072;
#pragma unroll
            for (int j = 0; j < 4; ++j) B[(it + 2) % 3][j] = *(const short8*)(bn + j * 64);
        }
        __builtin_amdgcn_sched_barrier(0);
        // compute tile it
        const char* Xc = smem + (it % 3) * 8192;
        short8 A[4];
#pragma unroll
        for (int i = 0; i < 4; ++i)
            A[i] = *(const short8*)(Xc + aoff + i * 256);
#pragma unroll
        for (int i = 0; i < 4; ++i)
#pragma unroll
            for (int j = 0; j < 4; ++j)
                acc[i][j] = __builtin_amdgcn_mfma_f32_16x16x32_bf16(A[i], B[it % 3][j], acc[i][j], 0, 0, 0);
    }

    // ---- epilogue: per-row (min, argmin, 2ndmin) over this 128-code tile.
    float se[4];
#pragma unroll
    for (int j = 0; j < 4; ++j) se[j] = sume[col0 + 64 * wx + 16 * j + l15];

    __syncthreads();   // all waves done reading LDS before scratch overlays it
    float* pv1 = (float*)smem;             // [128][8]
    float* pv2 = (float*)(smem + 4096);    // [128][8]
    int*   pk1 = (int*)(smem + 8192);      // [128][8]

#pragma unroll
    for (int i = 0; i < 4; ++i) {
#pragma unroll
        for (int reg = 0; reg < 4; ++reg) {
            float v1 = FLT_MAX, v2 = FLT_MAX; int k1 = 0;
#pragma unroll
            for (int j = 0; j < 4; ++j) {
                const float s = __builtin_fmaf(-2.f, acc[i][j][reg], se[j]);
                const int c = col0 + 64 * wx + 16 * j + l15;
                if (s < v1) { v2 = v1; v1 = s; k1 = c; }
                else        { v2 = fminf(v2, s); }
            }
            // merge groups of 4 l15-lanes (exact ties leave l2nd==lmin -> the
            // rescore full-scans the tile, so tie-side argmin choice is moot)
#pragma unroll
            for (int m = 1; m <= 2; m <<= 1) {
                const float ov1 = __shfl_xor(v1, m, 64);
                const int   ok1 = __shfl_xor(k1, m, 64);
                const float ov2 = __shfl_xor(v2, m, 64);
                const float nv2 = fminf(fmaxf(v1, ov1), fminf(v2, ov2));
                if (ov1 < v1) { v1 = ov1; k1 = ok1; }
                v2 = nv2;
            }
            if ((l15 & 3) == 0) {
                const int rowl = 64 * wy + 16 * i + 4 * q4 + reg;
                const int c8   = wx * 4 + (l15 >> 2);
                const int slot = rowl * 8 + ((c8 + rowl) & 7);   // rotation swizzle
                pv1[slot] = v1; pv2[slot] = v2; pk1[slot] = k1;
            }
        }
    }
    __syncthreads();
    if (tid < 128) {
        float g1 = FLT_MAX, g2 = FLT_MAX; int gk = 0;
#pragma unroll
        for (int c = 0; c < 8; ++c) {
            const int slot = tid * 8 + ((c + tid) & 7);
            const float p1 = pv1[slot];
            const float p2 = pv2[slot];
            const int   pk = pk1[slot];
            if (p1 < g1) { g2 = fminf(g1, p2); g1 = p1; gk = pk; }
            else         { g2 = fminf(g2, p1); }
        }
        // transposed stat layout [nb][row]: 512 B contiguous per array
        const size_t o = (size_t)nb * NR + row0 + tid;
        lmin[o] = g1; l2nd[o] = g2; lidx[o] = gk;
    }
}

// exact rescore of provably-covering candidate set; one wave per row.
// margin = 2*(2^-7*||x||*||e||max + 6.5e-5): bf16-RNE dot error bound + two
// half-ulp(512) roundings in the exact formula, doubled for two-sidedness.
// Round-10: PROVABLY-EXACT single-candidate shortcut. The margin proof
// guarantees the candidate set (singles + full tiles) contains the argmin;
// when |set| == 1 (nS==1 && bf==0) the sole candidate IS the argmin -- no
// distance evaluation, no e-gather, no x staging. Output bit-identical to
// evaluating it (old path computed its dist and returned its index).
// Multi-candidate rows run the ORIGINAL EVAL code byte-identical.
// All rescore LDS (xr[w], list[w]) is wave-private, so __syncthreads is
// replaced by a wave-local lgkmcnt fence -- early-returning waves cannot
// deadlock a block barrier.
__global__ __launch_bounds__(256) void rescore_kernel(
        const float* __restrict__ x, const float* __restrict__ e,
        const float* __restrict__ sumx, const float* __restrict__ sume,
        const float* __restrict__ semax,
        const float* __restrict__ lmin, const float* __restrict__ l2nd,
        const int* __restrict__ lidx, int* __restrict__ inds) {
    __shared__ float xr[4][DDIM];
    __shared__ int list[4][64];

    const int w = threadIdx.x >> 6, lane = threadIdx.x & 63;
    const int row = blockIdx.x * 4 + w;

    // transposed stat layout [tile][row] (written coalesced by the gemm)
    const float lm = lmin[(size_t)lane * NR + row];
    const float l2 = l2nd[(size_t)lane * NR + row];
    const int   li = lidx[(size_t)lane * NR + row];

    float mr = lm;
#pragma unroll
    for (int m = 1; m < 64; m <<= 1) mr = fminf(mr, __shfl_xor(mr, m, 64));

    const float sx  = sumx[row];
    const float thr = mr + (0.0157f * sqrtf(sx) * semax[0] + 1.4e-4f);

    const bool single = (lm <= thr) && (l2 > thr);
    const unsigned long long bs = __ballot(single);
    const int nS = __popcll(bs);
    unsigned long long bf = __ballot(l2 <= thr);

    // |candidate set| == 1 -> that candidate is the argmin (margin proof).
    if (nS == 1 && bf == 0ull) {
        const int win = __shfl(li, __ffsll((long long)bs) - 1, 64);
        if (lane == 0) inds[row] = win;
        return;
    }

    const int pos = __popcll(bs & ((1ull << lane) - 1ull));
    if (single) list[w][pos] = li;

    {
        const float* px = x + (size_t)row * DDIM + lane * 8;
        *(float4*)(&xr[w][lane * 8])     = *(const float4*)(px);
        *(float4*)(&xr[w][lane * 8 + 4]) = *(const float4*)(px + 4);
    }
    // wave-local LDS fence: xr[w]/list[w] written and read by this wave only
    asm volatile("s_waitcnt lgkmcnt(0)" ::: "memory");

    float bd = FLT_MAX; int bk = 0x7fffffff;
    // exact dist: float4 loads, FMA order identical to all prior rounds
#define EVAL(KK)                                                             \
    {                                                                        \
        const int k_ = (KK);                                                 \
        const float4* ep4 = (const float4*)(e + ((size_t)k_ << 9));          \
        float dot = 0.f;                                                     \
        _Pragma("unroll 4")                                                  \
        for (int d4 = 0; d4 < 128; ++d4) {                                   \
            const float4 ev = ep4[d4];                                       \
            const float4 xv = *(const float4*)(&xr[w][d4 * 4]);              \
            dot = __builtin_fmaf(xv.x, ev.x, dot);                           \
            dot = __builtin_fmaf(xv.y, ev.y, dot);                           \
            dot = __builtin_fmaf(xv.z, ev.z, dot);                           \
            dot = __builtin_fmaf(xv.w, ev.w, dot);                           \
        }                                                                    \
        const float t1   = __fadd_rn(sx, sume[k_]);                          \
        const float dist = __fsub_rn(t1, __fadd_rn(dot, dot));               \
        if (dist < bd || (dist == bd && k_ < bk)) { bd = dist; bk = k_; }    \
    }

    if (lane < nS) EVAL(list[w][lane]);
    while (bf) {
        const int t = __ffsll((long long)bf) - 1;
        bf &= bf - 1;
        EVAL(128 * t + lane);
        EVAL(128 * t + 64 + lane);
    }
#undef EVAL

#pragma unroll
    for (int m = 1; m < 64; m <<= 1) {
        const float od = __shfl_xor(bd, m, 64);
        const int   ok = __shfl_xor(bk, m, 64);
        if (od < bd || (od == bd && ok < bk)) { bd = od; bk = ok; }
    }
    if (lane == 0) inds[row] = bk;
}

// out = x + (e[ind] - x), exact elementwise fp32 STE
__global__ __launch_bounds__(256) void writeout_kernel(const float* __restrict__ x,
                                                       const float* __restrict__ e,
                                                       const int* __restrict__ inds,
                                                       float* __restrict__ out) {
    const int t  = blockIdx.x * blockDim.x + threadIdx.x;
    const int n  = t >> 7;
    const int dq = (t & 127) * 4;
    const int ind = inds[n];
    const float4 xv = *(const float4*)(x + (size_t)n * DDIM + dq);
    const float4 ev = *(const float4*)(e + (size_t)ind * DDIM + dq);
    float4 o;
    o.x = __fadd_rn(xv.x, __fsub_rn(ev.x, xv.x));
    o.y = __fadd_rn(xv.y, __fsub_rn(ev.y, xv.y));
    o.z = __fadd_rn(xv.z, __fsub_rn(ev.z, xv.z));
    o.w = __fadd_rn(xv.w, __fsub_rn(ev.w, xv.w));
    *(float4*)(out + (size_t)n * DDIM + dq) = o;
}

extern "C" void kernel_launch(void* const* d_in, const int* in_sizes, int n_in,
                              void* d_out, int out_size, void* d_ws, size_t ws_size,
                              hipStream_t stream) {
    const float* lat = (const float*)d_in[0];   // (16,2048,512) fp32
    const float* emb = (const float*)d_in[1];   // (8192,512) fp32
    float* out = (float*)d_out;

    char* ws = (char*)d_ws;
    size_t off = 0;
    float*    sume  = (float*)(ws + off);    off += (size_t)KC * 4;
    float*    sumx  = (float*)(ws + off);    off += (size_t)NR * 4;
    float*    semax = (float*)(ws + off);    off += 256;
    float*    lmin  = (float*)(ws + off);    off += (size_t)NR * NTILE * 4;
    float*    l2nd  = (float*)(ws + off);    off += (size_t)NR * NTILE * 4;
    int*      lidx  = (int*)  (ws + off);    off += (size_t)NR * NTILE * 4;
    int*      inds  = (int*)  (ws + off);    off += (size_t)NR * 4;
    unsigned* xb    = (unsigned*)(ws + off); off += (size_t)NR * DDIM * 2;
    unsigned* ebT   = (unsigned*)(ws + off); off += (size_t)KC * DDIM * 2;

    lat_prep_kernel<<<NR / 32, 256, 0, stream>>>(lat, xb, sumx);
    emb_prep_kernel<<<KC / 32, 256, 0, stream>>>(emb, ebT, sume);
    semax_kernel<<<1, 256, 0, stream>>>(sume, semax);
    gemm_filter_kernel<<<(NR / 128) * NTILE, 256, 0, stream>>>(xb, ebT, sume, lmin, l2nd, lidx);
    rescore_kernel<<<NR / 4, 256, 0, stream>>>(lat, emb, sumx, sume, semax, lmin, l2nd, lidx, inds);
    writeout_kernel<<<(NR * DDIM / 4) / 256, 256, 0, stream>>>(lat, emb, inds, out);
}